// Round 12
// baseline (257.547 us; speedup 1.0000x reference)
//
#include <hip/hip_runtime.h>
#include <hip/hip_bf16.h>
#include <stdint.h>

// B=4, S=8192, E=1024, heads=16 -> math collapses to:
//   Q = x @ W1[0:1024].T ; A = per-64-col-block softmax(Q/4) ; out = A @ W2.T
static constexpr int MTOT = 32768;
static constexpr int KD   = 1024;
static constexpr int ND   = 1024;

static constexpr int BM = 256, BN = 256, BK = 64;
static constexpr int NT = KD / BK;              // 16 K-tiles (even)
static constexpr int BUF_BYTES = 32768;         // per-buffer: A only (256x64 bf16)
static constexpr int HALF = 16384;              // one A staging unit (128 rows x 64 cols)

typedef __bf16 bf16x8 __attribute__((ext_vector_type(8)));
typedef float  f32x4  __attribute__((ext_vector_type(4)));

__device__ __forceinline__ unsigned short f2bf_rne(float f) {
  union { float f; uint32_t u; } c; c.f = f;
  uint32_t u = c.u;
  return (unsigned short)((u + 0x7fffu + ((u >> 16) & 1u)) >> 16);
}

__global__ void cast_f32_to_bf16(const float* __restrict__ src,
                                 unsigned short* __restrict__ dst, int n4) {
  int idx = blockIdx.x * blockDim.x + threadIdx.x;
  int stride = gridDim.x * blockDim.x;
  for (int i = idx; i < n4; i += stride) {
    float4 v = reinterpret_cast<const float4*>(src)[i];
    ushort4 o;
    o.x = f2bf_rne(v.x); o.y = f2bf_rne(v.y);
    o.z = f2bf_rne(v.z); o.w = f2bf_rne(v.w);
    reinterpret_cast<ushort4*>(dst)[i] = o;
  }
}

__device__ __forceinline__ void gload_lds16(const void* g, void* lds) {
  __builtin_amdgcn_global_load_lds(
      (const __attribute__((address_space(1))) unsigned int*)g,
      (__attribute__((address_space(3))) unsigned int*)lds, 16, 0, 0);
}

// r12: B out of LDS. 256x256 tile, BK=64, 8 waves (2Mx4N), LDS holds ONLY the
// A double-buffer (2x32KB). B fragments load straight from global (L2-hot,
// 16B/lane dwordx4) one phase ahead of use into registers. Cuts per-tile LDS
// traffic from 256KB to 160KB. Keeps r7-proven: T1 XCD swizzle, T2 LDS
// swizzle on A, counted vmcnt (never 0 in loop), 3 barriers/K-tile
// {P2-end, P4-pre, P4-end}, setprio, 16x16x32 MFMA.
template <int SOFTMAX>
__global__ __launch_bounds__(512, 2)
void gemm8(const unsigned short* __restrict__ A,
           const unsigned short* __restrict__ Bm,
           void* __restrict__ Cout) {
  extern __shared__ __align__(16) char ldsc[];

  const int tid  = threadIdx.x;
  const int lane = tid & 63;
  const int wid  = tid >> 6;
  const int wm = wid >> 2, wn = wid & 3;       // wave tile: 128 rows x 64 cols
  const int fr = lane & 15, fq = lane >> 4;

  // T1: bijective XCD swizzle (512 blocks, 8 XCDs, 64 blocks/chunk).
  const int bid0 = blockIdx.x;
  const int bid  = ((bid0 & 7) << 6) | (bid0 >> 3);
  const int brow = (bid >> 2) * BM;
  const int bcol = (bid & 3) * BN;

  // A staging: linear LDS dest + inverse-swizzled global src (rule #21).
  const int srow  = tid >> 3;                              // 0..63
  const int sslot = (tid & 7) ^ (srow & 7);
  const unsigned short* gA = A + (size_t)(brow + srow) * KD + sslot * 8;

  f32x4  acc[8][4] = {};
  bf16x8 a0[4][2], a1[4][2], bA[2][2], bB[2][2];

  // Stage one A half-tile (128 rows x 64 cols = 16KB) into buffer b.
  auto STAGE = [&](int h, int kt, int b) {
    const unsigned short* gu = gA + (size_t)(h * 128) * KD + kt * BK;
    char* du = ldsc + b * BUF_BYTES + h * HALF + (wid << 10);
    gload_lds16(gu, du);
    gload_lds16(gu + (size_t)64 * KD, du + 8192);
  };

  auto rdA = [&](int b, bf16x8 (*dst)[2], int mBase) {
    const char* base = ldsc + b * BUF_BYTES + wm * HALF;
    #pragma unroll
    for (int mm = 0; mm < 4; ++mm) {
      const int r = (mBase + mm) * 16 + fr;
      #pragma unroll
      for (int ks = 0; ks < 2; ++ks)
        dst[mm][ks] = *(const bf16x8*)(base + (r << 7) +
                        ((ks * 64 + fq * 16) ^ ((r & 7) << 4)));
    }
  };
  // B fragments straight from global (L2-resident panel, 16B/lane).
  auto gldB = [&](int kt, int nBase, bf16x8 (*dst)[2]) {
    #pragma unroll
    for (int nn = 0; nn < 2; ++nn) {
      const size_t r = (size_t)(bcol + wn * 64 + (nBase + nn) * 16 + fr);
      #pragma unroll
      for (int ks = 0; ks < 2; ++ks)
        dst[nn][ks] = *(const bf16x8*)(Bm + r * KD + kt * BK + ks * 32 + fq * 8);
    }
  };
  auto MFMA16 = [&](int mBase, int nBase, bf16x8 (*af)[2], bf16x8 (*bf)[2]) {
    __builtin_amdgcn_s_setprio(1);
    #pragma unroll
    for (int ks = 0; ks < 2; ++ks)
      #pragma unroll
      for (int mm = 0; mm < 4; ++mm)
        #pragma unroll
        for (int nn = 0; nn < 2; ++nn)
          acc[mBase + mm][nBase + nn] = __builtin_amdgcn_mfma_f32_16x16x32_bf16(
              af[mm][ks], bf[nn][ks], acc[mBase + mm][nBase + nn], 0, 0, 0);
    __builtin_amdgcn_s_setprio(0);
  };

  // K-tile step. LDS hazards are A-only:
  //  - cur.A reads (P1/P2) retire before P2-end barrier; STAGE into cur at
  //    P3/P4 comes after it.
  //  - A(T+1) landed for all waves: vmcnt(4) + P4-pre barrier before next
  //    iter's rdA(nxt).
  //  vmcnt audit at P4: outstanding = [A(T+1)x4, bA/bB frags (use-waited by
  //  compiler), A(T+2)x4] -> vmcnt(4) retires everything except A(T+2).
  //  Never 0 in the loop. P4-end barrier pins gldB(bA) issue ahead of its
  //  next-tile P1 use (and keeps waves phase-locked).
  auto tileStep = [&](int T, int cur, int nxt) {
    const int tp1 = (T + 1 < NT) ? T + 1 : NT - 1;
    const int tp2 = (T + 2 < NT) ? T + 2 : NT - 1;

    // P1
    rdA(cur, a0, 0);
    MFMA16(0, 0, a0, bA);

    // P2 — issue B n23 frags for THIS tile (used at P3, ~1 cluster lead).
    rdA(cur, a1, 4);
    gldB(T, 2, bB);
    MFMA16(4, 0, a1, bA);
    __builtin_amdgcn_s_barrier();            // P2-end: all cur.A reads retired

    // P3
    STAGE(0, tp2, cur);
    MFMA16(4, 2, a1, bB);

    // P4
    STAGE(1, tp2, cur);
    asm volatile("s_waitcnt vmcnt(4)" ::: "memory"); // A(T+1) landed; A(T+2) in flight
    __builtin_amdgcn_s_barrier();            // P4-pre: A(T+1) visible to all
    gldB(tp1, 0, bA);                        // B n01 for tile T+1 (lead >= 1 cluster)
    MFMA16(0, 2, a0, bB);
    __builtin_amdgcn_s_barrier();            // P4-end
  };

  // --- prologue: bA(tile0) first, then A tiles 0,1 (order fixes vmcnt count) ---
  gldB(0, 0, bA);                                    // 8 frag loads (oldest)
  STAGE(0, 0, 0); STAGE(1, 0, 0);                    // A tile0 -> buf0
  STAGE(0, 1, 1); STAGE(1, 1, 1);                    // A tile1 -> buf1
  asm volatile("s_waitcnt vmcnt(4)" ::: "memory");   // bA + A(0) landed; A(1) in flight
  __builtin_amdgcn_s_barrier();

  for (int T = 0; T < NT; T += 2) {
    tileStep(T,     0, 1);
    tileStep(T + 1, 1, 0);
  }

  if constexpr (SOFTMAX) {
    // logits = acc/4; softmax over the wave's 64-col block (= one head block)
    unsigned short* attn = reinterpret_cast<unsigned short*>(Cout);
    constexpr float CEXP = 0.25f * 1.44269504088896340736f; // log2(e)/4
    #pragma unroll
    for (int m = 0; m < 8; ++m) {
      const int row = brow + wm * 128 + m * 16 + fq * 4;
      #pragma unroll
      for (int j = 0; j < 4; ++j) {
        float v0 = acc[m][0][j], v1 = acc[m][1][j];
        float v2 = acc[m][2][j], v3 = acc[m][3][j];
        float mx = fmaxf(fmaxf(v0, v1), fmaxf(v2, v3));
        #pragma unroll
        for (int s = 1; s < 16; s <<= 1) mx = fmaxf(mx, __shfl_xor(mx, s, 64));
        float p0 = exp2f((v0 - mx) * CEXP);
        float p1 = exp2f((v1 - mx) * CEXP);
        float p2 = exp2f((v2 - mx) * CEXP);
        float p3 = exp2f((v3 - mx) * CEXP);
        float sm = p0 + p1 + p2 + p3;
        #pragma unroll
        for (int s = 1; s < 16; s <<= 1) sm += __shfl_xor(sm, s, 64);
        const float inv = 1.0f / sm;
        unsigned short* dst =
            attn + (size_t)(row + j) * ND + (bcol + wn * 64 + fr);
        dst[0]  = f2bf_rne(p0 * inv);
        dst[16] = f2bf_rne(p1 * inv);
        dst[32] = f2bf_rne(p2 * inv);
        dst[48] = f2bf_rne(p3 * inv);
      }
    }
  } else {
    float* Cf = reinterpret_cast<float*>(Cout);
    #pragma unroll
    for (int m = 0; m < 8; ++m) {
      const int row = brow + wm * 128 + m * 16 + fq * 4;
      #pragma unroll
      for (int n = 0; n < 4; ++n) {
        const int col = bcol + wn * 64 + n * 16 + fr;
        #pragma unroll
        for (int j = 0; j < 4; ++j)
          Cf[(size_t)(row + j) * ND + col] = acc[m][n][j];
      }
    }
  }
}

extern "C" void kernel_launch(void* const* d_in, const int* in_sizes, int n_in,
                              void* d_out, int out_size, void* d_ws, size_t ws_size,
                              hipStream_t stream) {
  const float* x  = (const float*)d_in[0];   // [4,8192,1024] f32
  const float* W1 = (const float*)d_in[1];   // [3072,1024]  f32 (rows 0..1023 = Wq)
  const float* W2 = (const float*)d_in[2];   // [1024,1024]  f32
  float* out = (float*)d_out;

  char* ws = (char*)d_ws;
  unsigned short* xb   = (unsigned short*)(ws);
  unsigned short* w1b  = (unsigned short*)(ws + (size_t)67108864);
  unsigned short* w2b  = (unsigned short*)(ws + (size_t)69206016);
  unsigned short* attn = (unsigned short*)(ws + (size_t)71303168);

  hipFuncSetAttribute(reinterpret_cast<const void*>(gemm8<1>),
                      hipFuncAttributeMaxDynamicSharedMemorySize, 65536);
  hipFuncSetAttribute(reinterpret_cast<const void*>(gemm8<0>),
                      hipFuncAttributeMaxDynamicSharedMemorySize, 65536);

  cast_f32_to_bf16<<<2048, 256, 0, stream>>>(x,  xb,  MTOT * KD / 4);
  cast_f32_to_bf16<<<512,  256, 0, stream>>>(W1, w1b, KD * KD / 4);
  cast_f32_to_bf16<<<512,  256, 0, stream>>>(W2, w2b, KD * KD / 4);

  const int nblk = (MTOT / BM) * (ND / BN);   // 128 * 4 = 512
  gemm8<1><<<nblk, 512, 65536, stream>>>(xb, w1b, (void*)attn);
  gemm8<0><<<nblk, 512, 65536, stream>>>(attn, w2b, (void*)out);
}

// Round 13
// 193.908 us; speedup vs baseline: 1.3282x; 1.3282x over previous
//
#include <hip/hip_runtime.h>
#include <hip/hip_bf16.h>
#include <stdint.h>

// B=4, S=8192, E=1024, heads=16 -> math collapses to:
//   Q = x @ W1[0:1024].T ; A = per-64-col-block softmax(Q/4) ; out = A @ W2.T
static constexpr int MTOT = 32768;
static constexpr int KD   = 1024;
static constexpr int ND   = 1024;

static constexpr int BM = 256, BN = 256, BK = 64;
static constexpr int NT = KD / BK;              // 16 K-tiles (even)
static constexpr int BUF_BYTES = 65536;         // per-buffer: A 32K + B 32K
static constexpr int BOFF = 32768;              // B offset within buffer
static constexpr int HALF = 16384;              // one unit (128 rows x 64 cols bf16)

typedef __bf16 bf16x8 __attribute__((ext_vector_type(8)));
typedef float  f32x4  __attribute__((ext_vector_type(4)));

__device__ __forceinline__ unsigned short f2bf_rne(float f) {
  union { float f; uint32_t u; } c; c.f = f;
  uint32_t u = c.u;
  return (unsigned short)((u + 0x7fffu + ((u >> 16) & 1u)) >> 16);
}

__global__ void cast_f32_to_bf16(const float* __restrict__ src,
                                 unsigned short* __restrict__ dst, int n4) {
  int idx = blockIdx.x * blockDim.x + threadIdx.x;
  int stride = gridDim.x * blockDim.x;
  for (int i = idx; i < n4; i += stride) {
    float4 v = reinterpret_cast<const float4*>(src)[i];
    ushort4 o;
    o.x = f2bf_rne(v.x); o.y = f2bf_rne(v.y);
    o.z = f2bf_rne(v.z); o.w = f2bf_rne(v.w);
    reinterpret_cast<ushort4*>(dst)[i] = o;
  }
}

__device__ __forceinline__ void gload_lds16(const void* g, void* lds) {
  __builtin_amdgcn_global_load_lds(
      (const __attribute__((address_space(1))) unsigned int*)g,
      (__attribute__((address_space(3))) unsigned int*)lds, 16, 0, 0);
}

// r13: faithful m201 8-phase choreography. 256x256 tile, BK=64, 8 waves
// (2Mx4N), 128 KiB double-buffered LDS, T1 XCD swizzle, T2 LDS swizzle.
// Per phase: {ds_reads | stage 1 half-tile -> s_barrier -> lgkmcnt(0) ->
// setprio(1) -> 16 MFMA -> setprio(0) -> s_barrier}. vmcnt(6) once per
// K-tile at Ph4 (3 half-tiles stay in flight). Stage schedule:
//   Ph1: T+1.B1 -> nxt   (nxt last read at tile T-1, >=2 barriers back)
//   Ph2: T+2.A0 -> cur   (cur.A0 last read Ph1; retired at Ph1 lgkm0+barrier)
//   Ph3: T+2.A1 -> cur   (read Ph2; retired Ph2-end)
//   Ph4: T+2.B0 -> cur   (b01 read Ph1, b23 read Ph3; retired Ph3-end)
// vmcnt(6)@Ph4 queue: [T+1.A0,A1,B0 (from T-1), T+1.B1, T+2.A0,A1,B0] =
// 14 loads -> retires 8 = tile T+1 complete; 3 units in flight. Tail stages
// clamp to NT-1 (stale-write-only, counts preserved).
template <int SOFTMAX>
__global__ __launch_bounds__(512, 2)
void gemm8(const unsigned short* __restrict__ A,
           const unsigned short* __restrict__ Bm,
           void* __restrict__ Cout) {
  extern __shared__ __align__(16) char ldsc[];

  const int tid  = threadIdx.x;
  const int lane = tid & 63;
  const int wid  = tid >> 6;
  const int wm = wid >> 2, wn = wid & 3;       // wave tile: 128 rows x 64 cols
  const int fr = lane & 15, fq = lane >> 4;

  // T1: bijective XCD swizzle (512 blocks, 8 XCDs, 64 blocks/chunk).
  const int bid0 = blockIdx.x;
  const int bid  = ((bid0 & 7) << 6) | (bid0 >> 3);
  const int brow = (bid >> 2) * BM;
  const int bcol = (bid & 3) * BN;

  // staging: linear LDS dest + inverse-swizzled global src (rule #21).
  const int srow  = tid >> 3;                              // 0..63
  const int sslot = (tid & 7) ^ (srow & 7);
  const unsigned short* gA = A  + (size_t)(brow + srow) * KD + sslot * 8;
  const unsigned short* gB = Bm + (size_t)(bcol + srow) * KD + sslot * 8;

  f32x4  acc[8][4] = {};
  bf16x8 a0[4][2], a1[4][2], b01[2][2], b23[2][2];

  auto STAGE = [&](const unsigned short* g, int h, int kt, int b, int opOff) {
    const unsigned short* gu = g + (size_t)(h * 128) * KD + kt * BK;
    char* du = ldsc + b * BUF_BYTES + opOff + h * HALF + (wid << 10);
    gload_lds16(gu, du);
    gload_lds16(gu + (size_t)64 * KD, du + 8192);
  };

  auto rdA = [&](int b, bf16x8 (*dst)[2], int mBase) {
    const char* base = ldsc + b * BUF_BYTES + wm * HALF;
    #pragma unroll
    for (int mm = 0; mm < 4; ++mm) {
      const int r = (mBase + mm) * 16 + fr;
      #pragma unroll
      for (int ks = 0; ks < 2; ++ks)
        dst[mm][ks] = *(const bf16x8*)(base + (r << 7) +
                        ((ks * 64 + fq * 16) ^ ((r & 7) << 4)));
    }
  };
  auto rdB = [&](int b, int nBase, bf16x8 (*dst)[2]) {
    const char* base = ldsc + b * BUF_BYTES + BOFF + (wn >> 1) * HALF;
    #pragma unroll
    for (int nn = 0; nn < 2; ++nn) {
      const int r = (wn & 1) * 64 + (nBase + nn) * 16 + fr;
      #pragma unroll
      for (int ks = 0; ks < 2; ++ks)
        dst[nn][ks] = *(const bf16x8*)(base + (r << 7) +
                       ((ks * 64 + fq * 16) ^ ((r & 7) << 4)));
    }
  };
  auto MFMA16 = [&](int mBase, int nBase, bf16x8 (*af)[2], bf16x8 (*bf)[2]) {
    __builtin_amdgcn_s_setprio(1);
    #pragma unroll
    for (int ks = 0; ks < 2; ++ks)
      #pragma unroll
      for (int mm = 0; mm < 4; ++mm)
        #pragma unroll
        for (int nn = 0; nn < 2; ++nn)
          acc[mBase + mm][nBase + nn] = __builtin_amdgcn_mfma_f32_16x16x32_bf16(
              af[mm][ks], bf[nn][ks], acc[mBase + mm][nBase + nn], 0, 0, 0);
    __builtin_amdgcn_s_setprio(0);
  };

  auto tileStep = [&](int T, int cur, int nxt) {
    const int tp1 = (T + 1 < NT) ? T + 1 : NT - 1;
    const int tp2 = (T + 2 < NT) ? T + 2 : NT - 1;

    // Ph1: 12 reads | stage T+1.B1 -> nxt
    rdA(cur, a0, 0);
    rdB(cur, 0, b01);
    STAGE(gB, 1, tp1, nxt, BOFF);
    asm volatile("s_waitcnt lgkmcnt(8)" ::: "memory");
    __builtin_amdgcn_s_barrier();
    asm volatile("s_waitcnt lgkmcnt(0)" ::: "memory");
    MFMA16(0, 0, a0, b01);
    __builtin_amdgcn_s_barrier();

    // Ph2: 8 reads | stage T+2.A0 -> cur
    rdA(cur, a1, 4);
    STAGE(gA, 0, tp2, cur, 0);
    __builtin_amdgcn_s_barrier();
    asm volatile("s_waitcnt lgkmcnt(0)" ::: "memory");
    MFMA16(4, 0, a1, b01);
    __builtin_amdgcn_s_barrier();

    // Ph3: 4 reads | stage T+2.A1 -> cur
    rdB(cur, 2, b23);
    STAGE(gA, 1, tp2, cur, 0);
    __builtin_amdgcn_s_barrier();
    asm volatile("s_waitcnt lgkmcnt(0)" ::: "memory");
    MFMA16(4, 2, a1, b23);
    __builtin_amdgcn_s_barrier();

    // Ph4: 0 reads | stage T+2.B0 -> cur | per-tile counted vmcnt
    STAGE(gB, 0, tp2, cur, BOFF);
    asm volatile("s_waitcnt vmcnt(6)" ::: "memory"); // tile T+1 landed; 3 units fly
    __builtin_amdgcn_s_barrier();
    MFMA16(0, 2, a0, b23);
    __builtin_amdgcn_s_barrier();
  };

  // --- prologue: tile0 (4 units) + tile1 (A0,A1,B0) ---
  STAGE(gB, 0, 0, 0, BOFF); STAGE(gB, 1, 0, 0, BOFF);
  STAGE(gA, 0, 0, 0, 0);    STAGE(gA, 1, 0, 0, 0);
  STAGE(gA, 0, 1, 1, 0);    STAGE(gA, 1, 1, 1, 0);
  STAGE(gB, 0, 1, 1, BOFF);
  asm volatile("s_waitcnt vmcnt(6)" ::: "memory");   // tile0 landed; 3 units in flight
  __builtin_amdgcn_s_barrier();

  for (int T = 0; T < NT; T += 2) {
    tileStep(T,     0, 1);
    tileStep(T + 1, 1, 0);
  }

  if constexpr (SOFTMAX) {
    // logits = acc/4; softmax over the wave's 64-col block (= one head block)
    unsigned short* attn = reinterpret_cast<unsigned short*>(Cout);
    constexpr float CEXP = 0.25f * 1.44269504088896340736f; // log2(e)/4
    #pragma unroll
    for (int m = 0; m < 8; ++m) {
      const int row = brow + wm * 128 + m * 16 + fq * 4;
      #pragma unroll
      for (int j = 0; j < 4; ++j) {
        float v0 = acc[m][0][j], v1 = acc[m][1][j];
        float v2 = acc[m][2][j], v3 = acc[m][3][j];
        float mx = fmaxf(fmaxf(v0, v1), fmaxf(v2, v3));
        #pragma unroll
        for (int s = 1; s < 16; s <<= 1) mx = fmaxf(mx, __shfl_xor(mx, s, 64));
        float p0 = exp2f((v0 - mx) * CEXP);
        float p1 = exp2f((v1 - mx) * CEXP);
        float p2 = exp2f((v2 - mx) * CEXP);
        float p3 = exp2f((v3 - mx) * CEXP);
        float sm = p0 + p1 + p2 + p3;
        #pragma unroll
        for (int s = 1; s < 16; s <<= 1) sm += __shfl_xor(sm, s, 64);
        const float inv = 1.0f / sm;
        unsigned short* dst =
            attn + (size_t)(row + j) * ND + (bcol + wn * 64 + fr);
        dst[0]  = f2bf_rne(p0 * inv);
        dst[16] = f2bf_rne(p1 * inv);
        dst[32] = f2bf_rne(p2 * inv);
        dst[48] = f2bf_rne(p3 * inv);
      }
    }
  } else {
    float* Cf = reinterpret_cast<float*>(Cout);
    #pragma unroll
    for (int m = 0; m < 8; ++m) {
      const int row = brow + wm * 128 + m * 16 + fq * 4;
      #pragma unroll
      for (int n = 0; n < 4; ++n) {
        const int col = bcol + wn * 64 + n * 16 + fr;
        #pragma unroll
        for (int j = 0; j < 4; ++j)
          Cf[(size_t)(row + j) * ND + col] = acc[m][n][j];
      }
    }
  }
}

extern "C" void kernel_launch(void* const* d_in, const int* in_sizes, int n_in,
                              void* d_out, int out_size, void* d_ws, size_t ws_size,
                              hipStream_t stream) {
  const float* x  = (const float*)d_in[0];   // [4,8192,1024] f32
  const float* W1 = (const float*)d_in[1];   // [3072,1024]  f32 (rows 0..1023 = Wq)
  const float* W2 = (const float*)d_in[2];   // [1024,1024]  f32
  float* out = (float*)d_out;

  char* ws = (char*)d_ws;
  unsigned short* xb   = (unsigned short*)(ws);
  unsigned short* w1b  = (unsigned short*)(ws + (size_t)67108864);
  unsigned short* w2b  = (unsigned short*)(ws + (size_t)69206016);
  unsigned short* attn = (unsigned short*)(ws + (size_t)71303168);

  hipFuncSetAttribute(reinterpret_cast<const void*>(gemm8<1>),
                      hipFuncAttributeMaxDynamicSharedMemorySize, 131072);
  hipFuncSetAttribute(reinterpret_cast<const void*>(gemm8<0>),
                      hipFuncAttributeMaxDynamicSharedMemorySize, 131072);

  cast_f32_to_bf16<<<2048, 256, 0, stream>>>(x,  xb,  MTOT * KD / 4);
  cast_f32_to_bf16<<<512,  256, 0, stream>>>(W1, w1b, KD * KD / 4);
  cast_f32_to_bf16<<<512,  256, 0, stream>>>(W2, w2b, KD * KD / 4);

  const int nblk = (MTOT / BM) * (ND / BN);   // 128 * 4 = 512
  gemm8<1><<<nblk, 512, 131072, stream>>>(xb, w1b, (void*)attn);
  gemm8<0><<<nblk, 512, 131072, stream>>>(attn, w2b, (void*)out);
}

// Round 14
// 193.297 us; speedup vs baseline: 1.3324x; 1.0032x over previous
//
#include <hip/hip_runtime.h>
#include <hip/hip_bf16.h>
#include <stdint.h>

// B=4, S=8192, E=1024, heads=16 -> math collapses to:
//   Q = x @ W1[0:1024].T ; A = per-64-col-block softmax(Q/4) ; out = A @ W2.T
static constexpr int MTOT = 32768;
static constexpr int KD   = 1024;
static constexpr int ND   = 1024;

static constexpr int BM = 256, BN = 256, BK = 64;
static constexpr int NT = KD / BK;              // 16 K-tiles (even)
static constexpr int BUF_BYTES = 65536;         // per-buffer: A 32K + B 32K
static constexpr int BOFF = 32768;              // B offset within buffer
static constexpr int HALF = 16384;              // one unit (128 rows x 64 cols bf16)

typedef __bf16 bf16x8 __attribute__((ext_vector_type(8)));
typedef float  f32x4  __attribute__((ext_vector_type(4)));

__device__ __forceinline__ unsigned short f2bf_rne(float f) {
  union { float f; uint32_t u; } c; c.f = f;
  uint32_t u = c.u;
  return (unsigned short)((u + 0x7fffu + ((u >> 16) & 1u)) >> 16);
}

__global__ void cast_f32_to_bf16(const float* __restrict__ src,
                                 unsigned short* __restrict__ dst, int n4) {
  int idx = blockIdx.x * blockDim.x + threadIdx.x;
  int stride = gridDim.x * blockDim.x;
  for (int i = idx; i < n4; i += stride) {
    float4 v = reinterpret_cast<const float4*>(src)[i];
    ushort4 o;
    o.x = f2bf_rne(v.x); o.y = f2bf_rne(v.y);
    o.z = f2bf_rne(v.z); o.w = f2bf_rne(v.w);
    reinterpret_cast<ushort4*>(dst)[i] = o;
  }
}

__device__ __forceinline__ void gload_lds16(const void* g, void* lds) {
  __builtin_amdgcn_global_load_lds(
      (const __attribute__((address_space(1))) unsigned int*)g,
      (__attribute__((address_space(3))) unsigned int*)lds, 16, 0, 0);
}

// r14: persistent blocks. Grid 256 (1/CU), each block runs TWO 256-row tiles
// back-to-back; the bt=1 prologue staging is issued before the bt=0 epilogue
// so pass-2's pipeline fill overlaps pass-1's softmax/stores. K-loop body is
// r7-exact (87us best): 256x256, BK=64, 8 waves, 128 KiB dbuf LDS, T1 XCD
// swizzle, T2 LDS swizzle, counted vmcnt (never 0), 3 barriers/K-tile,
// setprio, 16x16x32 MFMA.
template <int SOFTMAX>
__global__ __launch_bounds__(512, 2)
void gemm8(const unsigned short* __restrict__ A,
           const unsigned short* __restrict__ Bm,
           void* __restrict__ Cout) {
  extern __shared__ __align__(16) char ldsc[];

  const int tid  = threadIdx.x;
  const int lane = tid & 63;
  const int wid  = tid >> 6;
  const int wm = wid >> 2, wn = wid & 3;       // wave tile: 128 rows x 64 cols
  const int fr = lane & 15, fq = lane >> 4;

  // T1: bijective XCD swizzle (256 blocks, 8 XCDs, 32 blocks/chunk).
  const int bid0 = blockIdx.x;
  const int bid  = ((bid0 & 7) << 5) | (bid0 >> 3);
  const int baseRow = (bid >> 2) * (2 * BM);   // two adjacent row tiles/block
  const int bcol    = (bid & 3) * BN;

  // staging: linear LDS dest + inverse-swizzled global src (rule #21).
  const int srow  = tid >> 3;                              // 0..63
  const int sslot = (tid & 7) ^ (srow & 7);
  const unsigned short* gB = Bm + (size_t)(bcol + srow) * KD + sslot * 8;
  const unsigned short* gA = A + (size_t)(baseRow + srow) * KD + sslot * 8;

  f32x4  acc[8][4] = {};
  bf16x8 a0[4][2], a1[4][2], bA[2][2], bB[2][2];

  auto STAGE = [&](const unsigned short* g, int h, int kt, int b, int opOff) {
    const unsigned short* gu = g + (size_t)(h * 128) * KD + kt * BK;
    char* du = ldsc + b * BUF_BYTES + opOff + h * HALF + (wid << 10);
    gload_lds16(gu, du);
    gload_lds16(gu + (size_t)64 * KD, du + 8192);
  };

  auto rdA = [&](int b, bf16x8 (*dst)[2], int mBase) {
    const char* base = ldsc + b * BUF_BYTES + wm * HALF;
    #pragma unroll
    for (int mm = 0; mm < 4; ++mm) {
      const int r = (mBase + mm) * 16 + fr;
      #pragma unroll
      for (int ks = 0; ks < 2; ++ks)
        dst[mm][ks] = *(const bf16x8*)(base + (r << 7) +
                        ((ks * 64 + fq * 16) ^ ((r & 7) << 4)));
    }
  };
  auto rdB = [&](int b, int nBase, bf16x8 (*dst)[2]) {
    const char* base = ldsc + b * BUF_BYTES + BOFF + (wn >> 1) * HALF;
    #pragma unroll
    for (int nn = 0; nn < 2; ++nn) {
      const int r = (wn & 1) * 64 + (nBase + nn) * 16 + fr;
      #pragma unroll
      for (int ks = 0; ks < 2; ++ks)
        dst[nn][ks] = *(const bf16x8*)(base + (r << 7) +
                       ((ks * 64 + fq * 16) ^ ((r & 7) << 4)));
    }
  };
  auto MFMA16 = [&](int mBase, int nBase, bf16x8 (*af)[2], bf16x8 (*bf)[2]) {
    __builtin_amdgcn_s_setprio(1);
    #pragma unroll
    for (int ks = 0; ks < 2; ++ks)
      #pragma unroll
      for (int mm = 0; mm < 4; ++mm)
        #pragma unroll
        for (int nn = 0; nn < 2; ++nn)
          acc[mBase + mm][nBase + nn] = __builtin_amdgcn_mfma_f32_16x16x32_bf16(
              af[mm][ks], bf[nn][ks], acc[mBase + mm][nBase + nn], 0, 0, 0);
    __builtin_amdgcn_s_setprio(0);
  };

  // r7-exact K-tile step. Barriers: P2-end, P4-pre(post-vmcnt), P4-end.
  auto tileStep = [&](int T, int cur, int nxt) {
    const int tp1 = (T + 1 < NT) ? T + 1 : NT - 1;
    const int tp2 = (T + 2 < NT) ? T + 2 : NT - 1;

    rdA(cur, a0, 0);
    STAGE(gB, 0, tp1, nxt, BOFF);
    MFMA16(0, 0, a0, bA);

    rdA(cur, a1, 4);
    STAGE(gB, 1, tp1, nxt, BOFF);
    MFMA16(4, 0, a1, bA);
    __builtin_amdgcn_s_barrier();            // P2-end: all cur.A reads retired

    rdB(cur, 2, bB);
    STAGE(gA, 0, tp2, cur, 0);
    MFMA16(4, 2, a1, bB);

    STAGE(gA, 1, tp2, cur, 0);
    asm volatile("s_waitcnt vmcnt(4)" ::: "memory"); // retires thru T+1; T+2.A flies
    __builtin_amdgcn_s_barrier();            // P4-pre: tile T+1 visible to all
    rdB(nxt, 0, bA);                         // tile T+1 b01; overlaps MFMA below
    MFMA16(0, 2, a0, bB);
    __builtin_amdgcn_s_barrier();            // P4-end
  };

  auto prologue = [&]() {   // 6 units; works with 0 or 4 stale loads in flight
    STAGE(gA, 0, 0, 0, 0);    STAGE(gA, 1, 0, 0, 0);
    STAGE(gB, 0, 0, 0, BOFF); STAGE(gB, 1, 0, 0, BOFF);
    STAGE(gA, 0, 1, 1, 0);    STAGE(gA, 1, 1, 1, 0);
    asm volatile("s_waitcnt vmcnt(4)" ::: "memory"); // tile0 landed; tile1.A flies
    __builtin_amdgcn_s_barrier();
    rdB(0, 0, bA);
  };

  auto epilogue = [&](int brow) {
    if constexpr (SOFTMAX) {
      unsigned short* attn = reinterpret_cast<unsigned short*>(Cout);
      constexpr float CEXP = 0.25f * 1.44269504088896340736f; // log2(e)/4
      #pragma unroll
      for (int m = 0; m < 8; ++m) {
        const int row = brow + wm * 128 + m * 16 + fq * 4;
        #pragma unroll
        for (int j = 0; j < 4; ++j) {
          float v0 = acc[m][0][j], v1 = acc[m][1][j];
          float v2 = acc[m][2][j], v3 = acc[m][3][j];
          float mx = fmaxf(fmaxf(v0, v1), fmaxf(v2, v3));
          #pragma unroll
          for (int s = 1; s < 16; s <<= 1) mx = fmaxf(mx, __shfl_xor(mx, s, 64));
          float p0 = exp2f((v0 - mx) * CEXP);
          float p1 = exp2f((v1 - mx) * CEXP);
          float p2 = exp2f((v2 - mx) * CEXP);
          float p3 = exp2f((v3 - mx) * CEXP);
          float sm = p0 + p1 + p2 + p3;
          #pragma unroll
          for (int s = 1; s < 16; s <<= 1) sm += __shfl_xor(sm, s, 64);
          const float inv = 1.0f / sm;
          unsigned short* dst =
              attn + (size_t)(row + j) * ND + (bcol + wn * 64 + fr);
          dst[0]  = f2bf_rne(p0 * inv);
          dst[16] = f2bf_rne(p1 * inv);
          dst[32] = f2bf_rne(p2 * inv);
          dst[48] = f2bf_rne(p3 * inv);
        }
      }
    } else {
      float* Cf = reinterpret_cast<float*>(Cout);
      #pragma unroll
      for (int m = 0; m < 8; ++m) {
        const int row = brow + wm * 128 + m * 16 + fq * 4;
        #pragma unroll
        for (int n = 0; n < 4; ++n) {
          const int col = bcol + wn * 64 + n * 16 + fr;
          #pragma unroll
          for (int j = 0; j < 4; ++j)
            Cf[(size_t)(row + j) * ND + col] = acc[m][n][j];
        }
      }
    }
  };

  // ---- pass 0 ----
  prologue();
  for (int T = 0; T < NT; T += 2) {
    tileStep(T,     0, 1);
    tileStep(T + 1, 1, 0);
  }
  // ---- seam: stage pass-1 prologue BEFORE pass-0 epilogue ----
  // All LDS reads retired at the final P4-end barrier; in-flight queue = 4
  // tail-clamp loads. prologue() issues 12 more; vmcnt(4) retires old4 +
  // tile0 (8), leaves tile1.A in flight -- identical steady state. The
  // epilogue stores then overlap pass-1's first phases (L2-ack ~1-2us).
  gA = A + (size_t)(baseRow + BM + srow) * KD + sslot * 8;
  prologue();
  epilogue(baseRow);
  #pragma unroll
  for (int m = 0; m < 8; ++m)
    #pragma unroll
    for (int n = 0; n < 4; ++n)
      acc[m][n] = f32x4{0.f, 0.f, 0.f, 0.f};
  // ---- pass 1 ----
  for (int T = 0; T < NT; T += 2) {
    tileStep(T,     0, 1);
    tileStep(T + 1, 1, 0);
  }
  epilogue(baseRow + BM);
}

extern "C" void kernel_launch(void* const* d_in, const int* in_sizes, int n_in,
                              void* d_out, int out_size, void* d_ws, size_t ws_size,
                              hipStream_t stream) {
  const float* x  = (const float*)d_in[0];   // [4,8192,1024] f32
  const float* W1 = (const float*)d_in[1];   // [3072,1024]  f32 (rows 0..1023 = Wq)
  const float* W2 = (const float*)d_in[2];   // [1024,1024]  f32
  float* out = (float*)d_out;

  char* ws = (char*)d_ws;
  unsigned short* xb   = (unsigned short*)(ws);
  unsigned short* w1b  = (unsigned short*)(ws + (size_t)67108864);
  unsigned short* w2b  = (unsigned short*)(ws + (size_t)69206016);
  unsigned short* attn = (unsigned short*)(ws + (size_t)71303168);

  hipFuncSetAttribute(reinterpret_cast<const void*>(gemm8<1>),
                      hipFuncAttributeMaxDynamicSharedMemorySize, 131072);
  hipFuncSetAttribute(reinterpret_cast<const void*>(gemm8<0>),
                      hipFuncAttributeMaxDynamicSharedMemorySize, 131072);

  cast_f32_to_bf16<<<2048, 256, 0, stream>>>(x,  xb,  MTOT * KD / 4);
  cast_f32_to_bf16<<<512,  256, 0, stream>>>(W1, w1b, KD * KD / 4);
  cast_f32_to_bf16<<<512,  256, 0, stream>>>(W2, w2b, KD * KD / 4);

  const int nblk = (MTOT / (2 * BM)) * (ND / BN);   // 64 * 4 = 256 (1 round)
  gemm8<1><<<nblk, 512, 131072, stream>>>(xb, w1b, (void*)attn);
  gemm8<0><<<nblk, 512, 131072, stream>>>(attn, w2b, (void*)out);
}

// Round 15
// 185.355 us; speedup vs baseline: 1.3895x; 1.0428x over previous
//
#include <hip/hip_runtime.h>
#include <hip/hip_bf16.h>
#include <stdint.h>

// B=4, S=8192, E=1024, heads=16 -> math collapses to:
//   Q = x @ W1[0:1024].T ; A = per-64-col-block softmax(Q/4) ; out = A @ W2.T
static constexpr int MTOT = 32768;
static constexpr int KD   = 1024;
static constexpr int ND   = 1024;

static constexpr int BM = 256, BN = 256, BK = 64;
static constexpr int NT = KD / BK;              // 16 K-tiles (even)
static constexpr int BUF_BYTES = 65536;         // per-buffer: A 32K + B 32K
static constexpr int BOFF = 32768;              // B offset within buffer
static constexpr int HALF = 16384;              // one unit (128 rows x 64 cols bf16)

typedef __bf16 bf16x8 __attribute__((ext_vector_type(8)));
typedef float  f32x4  __attribute__((ext_vector_type(4)));

__device__ __forceinline__ unsigned short f2bf_rne(float f) {
  union { float f; uint32_t u; } c; c.f = f;
  uint32_t u = c.u;
  return (unsigned short)((u + 0x7fffu + ((u >> 16) & 1u)) >> 16);
}

// One kernel for all three casts (x, W1q, W2) -- saves two dispatch barriers.
__global__ void cast_all(const float* __restrict__ x,
                         const float* __restrict__ W1,
                         const float* __restrict__ W2,
                         unsigned short* __restrict__ xb,
                         unsigned short* __restrict__ w1b,
                         unsigned short* __restrict__ w2b) {
  constexpr int n4x = MTOT * KD / 4;
  constexpr int n4w = KD * KD / 4;
  constexpr int total = n4x + 2 * n4w;
  int idx = blockIdx.x * blockDim.x + threadIdx.x;
  int stride = gridDim.x * blockDim.x;
  for (int i = idx; i < total; i += stride) {
    const float* s; unsigned short* d; int j;
    if (i < n4x)            { s = x;  d = xb;  j = i; }
    else if (i < n4x + n4w) { s = W1; d = w1b; j = i - n4x; }
    else                    { s = W2; d = w2b; j = i - n4x - n4w; }
    float4 v = reinterpret_cast<const float4*>(s)[j];
    ushort4 o;
    o.x = f2bf_rne(v.x); o.y = f2bf_rne(v.y);
    o.z = f2bf_rne(v.z); o.w = f2bf_rne(v.w);
    reinterpret_cast<ushort4*>(d)[j] = o;
  }
}

__device__ __forceinline__ void gload_lds16(const void* g, void* lds) {
  __builtin_amdgcn_global_load_lds(
      (const __attribute__((address_space(1))) unsigned int*)g,
      (__attribute__((address_space(3))) unsigned int*)lds, 16, 0, 0);
}

// r7-cohort skeleton (best, 189.3us): 256x256 tile, BK=64, 8 waves (2Mx4N),
// 128 KiB double-buffered LDS, counted vmcnt (never 0 in loop), T1 XCD
// swizzle, T2 LDS swizzle, 16x16x32 MFMA, setprio, 3 barriers/K-tile
// {P2-end, P4-pre(post-vmcnt), P4-end}.
// r15 change: GEMM2 epilogue stores vectorized via wave-private LDS
// transpose (LDS is dead after the loop; 16KB chunk per wave).
template <int SOFTMAX>
__global__ __launch_bounds__(512, 2)
void gemm8(const unsigned short* __restrict__ A,
           const unsigned short* __restrict__ Bm,
           void* __restrict__ Cout) {
  extern __shared__ __align__(16) char ldsc[];

  const int tid  = threadIdx.x;
  const int lane = tid & 63;
  const int wid  = tid >> 6;
  const int wm = wid >> 2, wn = wid & 3;       // wave tile: 128 rows x 64 cols
  const int fr = lane & 15, fq = lane >> 4;

  // T1: bijective XCD swizzle (512 blocks, 8 XCDs, 64 blocks/chunk).
  const int bid0 = blockIdx.x;
  const int bid  = ((bid0 & 7) << 6) | (bid0 >> 3);
  const int brow = (bid >> 2) * BM;
  const int bcol = (bid & 3) * BN;

  // staging: linear LDS dest + inverse-swizzled global src (rule #21).
  const int srow  = tid >> 3;                              // 0..63
  const int sslot = (tid & 7) ^ (srow & 7);
  const unsigned short* gA = A  + (size_t)(brow + srow) * KD + sslot * 8;
  const unsigned short* gB = Bm + (size_t)(bcol + srow) * KD + sslot * 8;

  f32x4  acc[8][4] = {};
  bf16x8 a0[4][2], a1[4][2], bA[2][2], bB[2][2];

  auto STAGE = [&](const unsigned short* g, int h, int kt, int b, int opOff) {
    const unsigned short* gu = g + (size_t)(h * 128) * KD + kt * BK;
    char* du = ldsc + b * BUF_BYTES + opOff + h * HALF + (wid << 10);
    gload_lds16(gu, du);
    gload_lds16(gu + (size_t)64 * KD, du + 8192);
  };

  auto rdA = [&](int b, bf16x8 (*dst)[2], int mBase) {
    const char* base = ldsc + b * BUF_BYTES + wm * HALF;
    #pragma unroll
    for (int mm = 0; mm < 4; ++mm) {
      const int r = (mBase + mm) * 16 + fr;
      #pragma unroll
      for (int ks = 0; ks < 2; ++ks)
        dst[mm][ks] = *(const bf16x8*)(base + (r << 7) +
                        ((ks * 64 + fq * 16) ^ ((r & 7) << 4)));
    }
  };
  auto rdB = [&](int b, int nBase, bf16x8 (*dst)[2]) {
    const char* base = ldsc + b * BUF_BYTES + BOFF + (wn >> 1) * HALF;
    #pragma unroll
    for (int nn = 0; nn < 2; ++nn) {
      const int r = (wn & 1) * 64 + (nBase + nn) * 16 + fr;
      #pragma unroll
      for (int ks = 0; ks < 2; ++ks)
        dst[nn][ks] = *(const bf16x8*)(base + (r << 7) +
                       ((ks * 64 + fq * 16) ^ ((r & 7) << 4)));
    }
  };
  auto MFMA16 = [&](int mBase, int nBase, bf16x8 (*af)[2], bf16x8 (*bf)[2]) {
    __builtin_amdgcn_s_setprio(1);
    #pragma unroll
    for (int ks = 0; ks < 2; ++ks)
      #pragma unroll
      for (int mm = 0; mm < 4; ++mm)
        #pragma unroll
        for (int nn = 0; nn < 2; ++nn)
          acc[mBase + mm][nBase + nn] = __builtin_amdgcn_mfma_f32_16x16x32_bf16(
              af[mm][ks], bf[nn][ks], acc[mBase + mm][nBase + nn], 0, 0, 0);
    __builtin_amdgcn_s_setprio(0);
  };

  // r7-exact K-tile step. Barriers: P2-end, P4-pre(post-vmcnt), P4-end.
  auto tileStep = [&](int T, int cur, int nxt) {
    const int tp1 = (T + 1 < NT) ? T + 1 : NT - 1;
    const int tp2 = (T + 2 < NT) ? T + 2 : NT - 1;

    rdA(cur, a0, 0);
    STAGE(gB, 0, tp1, nxt, BOFF);
    MFMA16(0, 0, a0, bA);

    rdA(cur, a1, 4);
    STAGE(gB, 1, tp1, nxt, BOFF);
    MFMA16(4, 0, a1, bA);
    __builtin_amdgcn_s_barrier();            // P2-end: all cur.A reads retired

    rdB(cur, 2, bB);
    STAGE(gA, 0, tp2, cur, 0);
    MFMA16(4, 2, a1, bB);

    STAGE(gA, 1, tp2, cur, 0);
    asm volatile("s_waitcnt vmcnt(4)" ::: "memory"); // retires thru T+1; T+2.A flies
    __builtin_amdgcn_s_barrier();            // P4-pre: tile T+1 visible to all
    rdB(nxt, 0, bA);                         // tile T+1 b01; overlaps MFMA below
    MFMA16(0, 2, a0, bB);
    __builtin_amdgcn_s_barrier();            // P4-end
  };

  // --- prologue: tile0 (4 units) + A halves of tile1 ---
  STAGE(gA, 0, 0, 0, 0);    STAGE(gA, 1, 0, 0, 0);
  STAGE(gB, 0, 0, 0, BOFF); STAGE(gB, 1, 0, 0, BOFF);
  STAGE(gA, 0, 1, 1, 0);    STAGE(gA, 1, 1, 1, 0);
  asm volatile("s_waitcnt vmcnt(4)" ::: "memory");   // tile0 landed; A(1) in flight
  __builtin_amdgcn_s_barrier();
  rdB(0, 0, bA);                                     // b01 of tile 0

  for (int T = 0; T < NT; T += 2) {
    tileStep(T,     0, 1);
    tileStep(T + 1, 1, 0);
  }

  if constexpr (SOFTMAX) {
    // logits = acc/4; softmax over the wave's 64-col block (= one head block)
    unsigned short* attn = reinterpret_cast<unsigned short*>(Cout);
    constexpr float CEXP = 0.25f * 1.44269504088896340736f; // log2(e)/4
    #pragma unroll
    for (int m = 0; m < 8; ++m) {
      const int row = brow + wm * 128 + m * 16 + fq * 4;
      #pragma unroll
      for (int j = 0; j < 4; ++j) {
        float v0 = acc[m][0][j], v1 = acc[m][1][j];
        float v2 = acc[m][2][j], v3 = acc[m][3][j];
        float mx = fmaxf(fmaxf(v0, v1), fmaxf(v2, v3));
        #pragma unroll
        for (int s = 1; s < 16; s <<= 1) mx = fmaxf(mx, __shfl_xor(mx, s, 64));
        float p0 = exp2f((v0 - mx) * CEXP);
        float p1 = exp2f((v1 - mx) * CEXP);
        float p2 = exp2f((v2 - mx) * CEXP);
        float p3 = exp2f((v3 - mx) * CEXP);
        float sm = p0 + p1 + p2 + p3;
        #pragma unroll
        for (int s = 1; s < 16; s <<= 1) sm += __shfl_xor(sm, s, 64);
        const float inv = 1.0f / sm;
        unsigned short* dst =
            attn + (size_t)(row + j) * ND + (bcol + wn * 64 + fr);
        dst[0]  = f2bf_rne(p0 * inv);
        dst[16] = f2bf_rne(p1 * inv);
        dst[32] = f2bf_rne(p2 * inv);
        dst[48] = f2bf_rne(p3 * inv);
      }
    }
  } else {
    // Vectorized f32 C-write: wave-private 16KB LDS chunk as transpose bounce.
    // Loop LDS is dead (final P4-end barrier passed; any still-outstanding
    // dead rdB reads only feed unused regs, and per-wave DS ordering queues
    // our writes after them).
    float* Cf = reinterpret_cast<float*>(Cout);
    char* wlds = ldsc + wid * 16384;
    #pragma unroll
    for (int h = 0; h < 2; ++h) {
      asm volatile("" ::: "memory");
      #pragma unroll
      for (int mm = 0; mm < 4; ++mm)
        #pragma unroll
        for (int n = 0; n < 4; ++n)
          #pragma unroll
          for (int j = 0; j < 4; ++j)
            *(float*)(wlds + (((mm * 16 + fq * 4 + j) << 6) + n * 16 + fr) * 4)
                = acc[4 * h + mm][n][j];
      asm volatile("s_waitcnt lgkmcnt(0)" ::: "memory"); // scatter visible
      const int rbase = brow + wm * 128 + h * 64;
      #pragma unroll
      for (int i = 0; i < 16; ++i) {
        const int idx16 = i * 64 + lane;     // 16B chunk id within 64x64 tile
        const int rl = idx16 >> 4;
        const int c4 = (idx16 & 15) << 2;
        f32x4 v = *(const f32x4*)(wlds + (size_t)idx16 * 16);
        *(f32x4*)(&Cf[(size_t)(rbase + rl) * ND + (bcol + wn * 64 + c4)]) = v;
      }
      asm volatile("s_waitcnt lgkmcnt(0)" ::: "memory"); // gather done pre-overwrite
    }
  }
}

extern "C" void kernel_launch(void* const* d_in, const int* in_sizes, int n_in,
                              void* d_out, int out_size, void* d_ws, size_t ws_size,
                              hipStream_t stream) {
  const float* x  = (const float*)d_in[0];   // [4,8192,1024] f32
  const float* W1 = (const float*)d_in[1];   // [3072,1024]  f32 (rows 0..1023 = Wq)
  const float* W2 = (const float*)d_in[2];   // [1024,1024]  f32
  float* out = (float*)d_out;

  char* ws = (char*)d_ws;
  unsigned short* xb   = (unsigned short*)(ws);
  unsigned short* w1b  = (unsigned short*)(ws + (size_t)67108864);
  unsigned short* w2b  = (unsigned short*)(ws + (size_t)69206016);
  unsigned short* attn = (unsigned short*)(ws + (size_t)71303168);

  hipFuncSetAttribute(reinterpret_cast<const void*>(gemm8<1>),
                      hipFuncAttributeMaxDynamicSharedMemorySize, 131072);
  hipFuncSetAttribute(reinterpret_cast<const void*>(gemm8<0>),
                      hipFuncAttributeMaxDynamicSharedMemorySize, 131072);

  cast_all<<<2048, 256, 0, stream>>>(x, W1, W2, xb, w1b, w2b);

  const int nblk = (MTOT / BM) * (ND / BN);   // 128 * 4 = 512
  gemm8<1><<<nblk, 512, 131072, stream>>>(xb, w1b, (void*)attn);
  gemm8<0><<<nblk, 512, 131072, stream>>>(attn, w2b, (void*)out);
}